// Round 10
// baseline (147.259 us; speedup 1.0000x reference)
//
#include <hip/hip_runtime.h>

typedef __bf16 bf16_t;
typedef __bf16 bf16x8 __attribute__((ext_vector_type(8)));
typedef __bf16 bf16x4 __attribute__((ext_vector_type(4)));
typedef float f32x4 __attribute__((ext_vector_type(4)));

#define HH 96
#define WW 96
#define CC 128
#define HD 32
#define KW 7

// bf16 weight slab offsets (elements) in ws: proj, fc1, fc2
#define W_PROJ 0
#define W_FC1  16384
#define W_FC2  81920
#define W_TOT  147456

#define PATCH 10
#define PSZ 100             // 10x10 patch rows
#define NPAD 112            // padded to 7 MFMA m-tiles
#define STR 136             // LDS row stride (bf16)
#define H1S 520             // mlp h1 LDS stride

// smem regions (bf16 element offsets), total 34816 ele = 69632 B -> 2 blk/CU
// R0: ks[112][STR] -> Pbuf[4][16][STR] -> x0s[16][STR] + h1s[16][520]
// R1: vt[128][STR]  (v transposed: [ch][patch_row])
// R2: qs[16][STR]  -> o_s[16][STR]
#define R0 0
#define R1 (NPAD * STR)          // 15232
#define R2 (R1 + 128 * STR)      // 32640
#define SME (R2 + 16 * STR)      // 34816

// fp32 -> bf16x8 (two float4 loads + cvt)
__device__ __forceinline__ bf16x8 cvt8(const float* __restrict__ p) {
    const f32x4 a = *(const f32x4*)p;
    const f32x4 b = *(const f32x4*)(p + 4);
    bf16x8 r;
    r[0] = (bf16_t)a[0]; r[1] = (bf16_t)a[1]; r[2] = (bf16_t)a[2]; r[3] = (bf16_t)a[3];
    r[4] = (bf16_t)b[0]; r[5] = (bf16_t)b[1]; r[6] = (bf16_t)b[2]; r[7] = (bf16_t)b[3];
    return r;
}

// NT-tile MFMA strip, A/W bf16 at tile origin, K-contiguous rows.
template <int NT>
__device__ __forceinline__ void mmaN(const bf16_t* __restrict__ A, int lda,
                                     const bf16_t* __restrict__ W, int ldb,
                                     int K, f32x4* acc) {
    const int lane = threadIdx.x & 63;
    const bf16_t* ap = A + (lane & 15) * lda + ((lane >> 4) * 8);
    const bf16_t* bp = W + (lane & 15) * ldb + ((lane >> 4) * 8);
    for (int k0 = 0; k0 < K; k0 += 32) {
        bf16x8 a = *(const bf16x8*)(ap + k0);
#pragma unroll
        for (int t = 0; t < NT; t++) {
            bf16x8 b = *(const bf16x8*)(bp + t * 16 * ldb + k0);
            acc[t] = __builtin_amdgcn_mfma_f32_16x16x32_bf16(a, b, acc[t], 0, 0, 0);
        }
    }
}

// Kernel A: cvt proj/fc1/fc2 fp32 -> bf16 slab in ws. 144 blocks.
// FIX (r10): round-9 branch used `base < 4*W_FC1`, reading 48K elems past
// proj_w's end into the fc1 slab -> corrupted fc1 weights (absmax 1.48).
__global__ __launch_bounds__(256) void k_cvt(const float* __restrict__ proj_w,
                                             const float* __restrict__ fc1_w,
                                             const float* __restrict__ fc2_w,
                                             bf16_t* __restrict__ wb) {
    const int idx = blockIdx.x * 256 + threadIdx.x;   // 36864 x4 chunks
    const int base = idx * 4;
    const float* src;
    if (base < W_FC1)      src = proj_w + base;            // [0,16384)
    else if (base < W_FC2) src = fc1_w + (base - W_FC1);   // [16384,81920)
    else                   src = fc2_w + (base - W_FC2);   // [81920,147456)
    const f32x4 a = *(const f32x4*)src;
    bf16x4 r;
    r[0] = (bf16_t)a[0]; r[1] = (bf16_t)a[1]; r[2] = (bf16_t)a[2]; r[3] = (bf16_t)a[3];
    *(bf16x4*)(wb + base) = r;
}

// ===========================================================================
// Kernel B: per 4x4-token tile: patch-QKV (redundant, 10x10) -> na2d -> proj
// -> MLP -> fp32 out. 576 blocks x 256 threads, everything through LDS.
// ===========================================================================
__global__ __launch_bounds__(256, 2) void k_block(
        const float* __restrict__ x,
        const float* __restrict__ qkv_w, const float* __restrict__ qkv_b,
        const bf16_t* __restrict__ wb,
        const float* __restrict__ proj_b, const float* __restrict__ fc1_b,
        const float* __restrict__ fc2_b,  float* __restrict__ out) {
    __shared__ __align__(16) bf16_t smem[SME];
    bf16_t* ks   = smem + R0;
    bf16_t* vt   = smem + R1;
    bf16_t* qs   = smem + R2;
    bf16_t* Pbuf = smem + R0;            // overlay after ks dead
    bf16_t* o_s  = smem + R2;            // overlay after qs dead
    bf16_t* x0s  = smem + R0;            // overlay after Pbuf dead
    bf16_t* h1s  = smem + R0 + 16 * STR; // next to x0s (disjoint)

    const int tid = threadIdx.x;
    const int w = tid >> 6, lane = tid & 63;
    const int g = lane >> 4, li = lane & 15;
    const int bid = blockIdx.x;
    const int i0 = (bid / 24) * 4, j0 = (bid % 24) * 4;
    const int pr0 = min(max(i0 - 3, 0), HH - PATCH);
    const int pc0 = min(max(j0 - 3, 0), WW - PATCH);
    const int oa = i0 - pr0, ob = j0 - pc0;   // own-token origin in patch
    const int head = w;

    // zero vt cols 112..127 (phase-2 K padding must be 0*finite)
    {
        const int row = tid >> 1, half = tid & 1;
        *(bf16x8*)(vt + row * STR + NPAD + half * 8) = (bf16x8){0,0,0,0,0,0,0,0};
    }

    // ---- QKV for the patch. wave w -> out cols [w*96, w*96+96). ----
    // A rows = patch rows (pad rows >=100 duplicate row 99: finite, masked),
    // k -> ks[row][ch], v -> vt[ch][row] (b64-packed transposed store),
    // q -> qs (own 16 tokens only, predicated).
    float bb6[6];
#pragma unroll
    for (int nt = 0; nt < 6; nt++) bb6[nt] = qkv_b[w * 96 + nt * 16 + li];

    for (int mt = 0; mt < 7; mt++) {
        const int arow = mt * 16 + li;
        const int r99 = min(arow, 99);
        const int pi = r99 / 10, pj = r99 - 10 * pi;
        const float* ax = x + ((pr0 + pi) * WW + (pc0 + pj)) * CC + g * 8;
        bf16x8 a[4];
#pragma unroll
        for (int k0 = 0; k0 < 4; k0++) a[k0] = cvt8(ax + k0 * 32);
#pragma unroll
        for (int nt = 0; nt < 6; nt++) {
            const int n = w * 96 + nt * 16 + li;
            const float* bp = qkv_w + n * CC + g * 8;
            f32x4 acc = {0.f, 0.f, 0.f, 0.f};
#pragma unroll
            for (int k0 = 0; k0 < 4; k0++)
                acc = __builtin_amdgcn_mfma_f32_16x16x32_bf16(a[k0], cvt8(bp + k0 * 32), acc, 0, 0, 0);
            const float bb = bb6[nt];
            const int part = n >> 7, c = n & 127;
            if (part == 0) {            // q: own tokens only
#pragma unroll
                for (int r = 0; r < 4; r++) {
                    const int row = mt * 16 + g * 4 + r;
                    if (row < PSZ) {
                        const int ppi = row / 10, ppj = row - 10 * ppi;
                        const int ta = ppi - oa, tb = ppj - ob;
                        if ((unsigned)ta < 4u && (unsigned)tb < 4u)
                            qs[(ta * 4 + tb) * STR + c] = (bf16_t)(acc[r] + bb);
                    }
                }
            } else if (part == 1) {     // k: [row][ch]
#pragma unroll
                for (int r = 0; r < 4; r++)
                    ks[(mt * 16 + g * 4 + r) * STR + c] = (bf16_t)(acc[r] + bb);
            } else {                    // v: transposed [ch][row], b64 pack
                bf16x4 pk;
#pragma unroll
                for (int r = 0; r < 4; r++) pk[r] = (bf16_t)(acc[r] + bb);
                *(bf16x4*)(vt + c * STR + mt * 16 + g * 4) = pk;
            }
        }
    }
    __syncthreads();

    // ---- phase 1: logits[16][112] = Q @ K^T, 7 MFMA (K=32 = head slice) ----
    f32x4 lg[7];
    {
        const bf16x8 aq = *(const bf16x8*)(qs + li * STR + head * HD + g * 8);
#pragma unroll
        for (int t = 0; t < 7; t++) {
            const bf16x8 bk = *(const bf16x8*)(ks + (t * 16 + li) * STR + head * HD + g * 8);
            lg[t] = __builtin_amdgcn_mfma_f32_16x16x32_bf16(aq, bk, (f32x4){0.f,0.f,0.f,0.f}, 0, 0, 0);
        }
    }
    // ---- mask + register softmax (row m=g*4+r, col nb=t*16+li) ----
    int lr[4], lc[4];
#pragma unroll
    for (int r = 0; r < 4; r++) {
        const int m = g * 4 + r;
        const int i = i0 + (m >> 2), j = j0 + (m & 3);
        lr[r] = min(max(i - 3, 0), HH - KW) - pr0;
        lc[r] = min(max(j - 3, 0), WW - KW) - pc0;
    }
    const float scale = 0.17677669529663687f;   // 1/sqrt(32)
#pragma unroll
    for (int t = 0; t < 7; t++) {
        const int col = t * 16 + li;
        const int pi = col / 10, pj = col - 10 * pi;
#pragma unroll
        for (int r = 0; r < 4; r++) {
            const bool valid = (col < PSZ) &&
                               ((unsigned)(pi - lr[r]) <= 6u) &&
                               ((unsigned)(pj - lc[r]) <= 6u);
            lg[t][r] = valid ? lg[t][r] * scale : -1e30f;   // select: NaN-safe
        }
    }
    f32x4 mx = lg[0], sm;
#pragma unroll
    for (int t = 1; t < 7; t++)
#pragma unroll
        for (int r = 0; r < 4; r++) mx[r] = fmaxf(mx[r], lg[t][r]);
#pragma unroll
    for (int off = 8; off; off >>= 1)
#pragma unroll
        for (int r = 0; r < 4; r++) mx[r] = fmaxf(mx[r], __shfl_xor(mx[r], off));
#pragma unroll
    for (int r = 0; r < 4; r++) sm[r] = 0.f;
#pragma unroll
    for (int t = 0; t < 7; t++)
#pragma unroll
        for (int r = 0; r < 4; r++) {
            lg[t][r] = __expf(lg[t][r] - mx[r]);   // pads -> 0
            sm[r] += lg[t][r];
        }
#pragma unroll
    for (int off = 8; off; off >>= 1)
#pragma unroll
        for (int r = 0; r < 4; r++) sm[r] += __shfl_xor(sm[r], off);
#pragma unroll
    for (int r = 0; r < 4; r++) sm[r] = 1.f / sm[r];

    __syncthreads();   // all ks/qs reads done before Pbuf overlays ks

    // ---- P bf16 into Pbuf (cols 112..127 zeroed) ----
    bf16_t* Pw = Pbuf + w * 16 * STR;
#pragma unroll
    for (int t = 0; t < 7; t++)
#pragma unroll
        for (int r = 0; r < 4; r++)
            Pw[(g * 4 + r) * STR + t * 16 + li] = (bf16_t)(lg[t][r] * sm[r]);
    *(bf16x4*)(Pw + (lane >> 2) * STR + NPAD + (lane & 3) * 4) = (bf16x4){0,0,0,0};
    __syncthreads();

    // ---- phase 2: O[16][32] = P @ V^T, 8 MFMA (K=128; pads are 0) ----
    f32x4 oA[2] = {};
#pragma unroll
    for (int ks0 = 0; ks0 < 128; ks0 += 32) {
        const bf16x8 a = *(const bf16x8*)(Pw + li * STR + ks0 + g * 8);
#pragma unroll
        for (int t2 = 0; t2 < 2; t2++) {
            const bf16x8 b = *(const bf16x8*)(vt + (head * HD + t2 * 16 + li) * STR + ks0 + g * 8);
            oA[t2] = __builtin_amdgcn_mfma_f32_16x16x32_bf16(a, b, oA[t2], 0, 0, 0);
        }
    }
    __syncthreads();   // Pbuf/vt reads done; qs dead -> o_s overlay

    // ---- o -> LDS [16][STR], cols head*32..+31 ----
#pragma unroll
    for (int t2 = 0; t2 < 2; t2++)
#pragma unroll
        for (int r = 0; r < 4; r++)
            o_s[(g * 4 + r) * STR + head * HD + t2 * 16 + li] = (bf16_t)oA[t2][r];
    __syncthreads();

    // ---- proj: x0[16][128]; wave w -> cols w*32.. ----
    {
        f32x4 acc[2] = {};
        mmaN<2>(o_s, STR, wb + W_PROJ + (w * 32) * CC, CC, CC, acc);
#pragma unroll
        for (int t = 0; t < 2; t++) {
            const int n = w * 32 + t * 16 + li;
            const float bb = proj_b[n];
#pragma unroll
            for (int r = 0; r < 4; r++)
                x0s[(g * 4 + r) * STR + n] = (bf16_t)(acc[t][r] + bb);
        }
    }
    __syncthreads();

    // ---- fc1 + gelu: h1[16][512]; wave w -> cols w*128.. ----
    {
        f32x4 acc[8] = {};
        mmaN<8>(x0s, STR, wb + W_FC1 + (w * 128) * CC, CC, CC, acc);
#pragma unroll
        for (int t = 0; t < 8; t++) {
            const int n = w * 128 + t * 16 + li;
            const float bb = fc1_b[n];
#pragma unroll
            for (int r = 0; r < 4; r++) {
                const int m = g * 4 + r;
                const float xv = acc[t][r] + bb;
                const float u = 0.7978845608028654f * (xv + 0.044715f * xv * xv * xv);
                const float e = __expf(2.f * u);
                const float gg = 0.5f * xv * (2.f - 2.f / (e + 1.f));
                h1s[m * H1S + n] = (bf16_t)gg;
            }
        }
    }
    __syncthreads();

    // ---- fc2: fp32 out; wave w -> cols w*32.. ----
    {
        f32x4 acc[2] = {};
        mmaN<2>(h1s, H1S, wb + W_FC2 + (w * 32) * (4 * CC), 4 * CC, 4 * CC, acc);
#pragma unroll
        for (int t = 0; t < 2; t++) {
            const int n = w * 32 + t * 16 + li;
            const float bb = fc2_b[n];
#pragma unroll
            for (int r = 0; r < 4; r++) {
                const int m = g * 4 + r;
                const int i = i0 + (m >> 2), j = j0 + (m & 3);
                float xv = acc[t][r] + bb;
                xv = fminf(fmaxf(xv, -1e4f), 1e4f);   // diagnostic clamp
                out[(i * WW + j) * CC + n] = xv;
            }
        }
    }
}

extern "C" void kernel_launch(void* const* d_in, const int* in_sizes, int n_in,
                              void* d_out, int out_size, void* d_ws, size_t ws_size,
                              hipStream_t stream) {
    const float* x      = (const float*)d_in[0];
    const float* qkv_w  = (const float*)d_in[1];
    const float* qkv_b  = (const float*)d_in[2];
    const float* proj_w = (const float*)d_in[3];
    const float* proj_b = (const float*)d_in[4];
    const float* fc1_w  = (const float*)d_in[5];
    const float* fc1_b  = (const float*)d_in[6];
    const float* fc2_w  = (const float*)d_in[7];
    const float* fc2_b  = (const float*)d_in[8];

    bf16_t* wb = (bf16_t*)d_ws;     // 147456-elem bf16 weight slab (288 KB)
    float* out = (float*)d_out;

    k_cvt  <<<144, 256, 0, stream>>>(proj_w, fc1_w, fc2_w, wb);
    k_block<<<576, 256, 0, stream>>>(x, qkv_w, qkv_b, wb,
                                     proj_b, fc1_b, fc2_b, out);
}

// Round 11
// 123.707 us; speedup vs baseline: 1.1904x; 1.1904x over previous
//
#include <hip/hip_runtime.h>

typedef __bf16 bf16_t;
typedef __bf16 bf16x8 __attribute__((ext_vector_type(8)));
typedef __bf16 bf16x4 __attribute__((ext_vector_type(4)));
typedef float f32x4 __attribute__((ext_vector_type(4)));

#define HH 96
#define WW 96
#define CC 128
#define HD 32
#define TOK (HH * WW)      // 9216
#define PLANE (TOK * CC)
#define KW 7

// bf16 weight slab offsets (elements) in ws
#define W_QKV  0
#define W_PROJ 49152
#define W_FC1  65536
#define W_FC2  131072
#define W_TOT  196608

#define PATCH 10
#define PSZ 100
#define NPAD 112            // 7 N-tiles of 16
#define STR 136             // LDS row stride (bf16)
#define H1S 520

// fp32 -> bf16x8
__device__ __forceinline__ bf16x8 cvt8(const float* __restrict__ p) {
    const f32x4 a = *(const f32x4*)p;
    const f32x4 b = *(const f32x4*)(p + 4);
    bf16x8 r;
    r[0] = (bf16_t)a[0]; r[1] = (bf16_t)a[1]; r[2] = (bf16_t)a[2]; r[3] = (bf16_t)a[3];
    r[4] = (bf16_t)b[0]; r[5] = (bf16_t)b[1]; r[6] = (bf16_t)b[2]; r[7] = (bf16_t)b[3];
    return r;
}

// NT-tile MFMA strip (bf16 A/W, K-contiguous rows, at tile origin).
// A-frag: lane holds A[lane&15][(lane>>4)*8+j]; B-frag: W[t*16+(lane&15)][...]
// C/D: reg r -> row (lane>>4)*4+r, col t*16+(lane&15)
template <int NT>
__device__ __forceinline__ void mmaN(const bf16_t* __restrict__ A, int lda,
                                     const bf16_t* __restrict__ W, int ldb,
                                     int K, f32x4* acc) {
    const int lane = threadIdx.x & 63;
    const bf16_t* ap = A + (lane & 15) * lda + ((lane >> 4) * 8);
    const bf16_t* bp = W + (lane & 15) * ldb + ((lane >> 4) * 8);
    for (int k0 = 0; k0 < K; k0 += 32) {
        bf16x8 a = *(const bf16x8*)(ap + k0);
#pragma unroll
        for (int t = 0; t < NT; t++) {
            bf16x8 b = *(const bf16x8*)(bp + t * 16 * ldb + k0);
            acc[t] = __builtin_amdgcn_mfma_f32_16x16x32_bf16(a, b, acc[t], 0, 0, 0);
        }
    }
}

// K1: convert all 4 fp32 weight mats -> bf16 slab. 192 blocks.
__global__ __launch_bounds__(256) void k_cvt(const float* __restrict__ qkv_w,
                                             const float* __restrict__ proj_w,
                                             const float* __restrict__ fc1_w,
                                             const float* __restrict__ fc2_w,
                                             bf16_t* __restrict__ wb) {
    const int base = (blockIdx.x * 256 + threadIdx.x) * 4;   // 49152 chunks
    const float* src;
    if (base < W_PROJ)     src = qkv_w  + base;
    else if (base < W_FC1) src = proj_w + (base - W_PROJ);
    else if (base < W_FC2) src = fc1_w  + (base - W_FC1);
    else                   src = fc2_w  + (base - W_FC2);
    const f32x4 a = *(const f32x4*)src;
    bf16x4 r;
    r[0] = (bf16_t)a[0]; r[1] = (bf16_t)a[1]; r[2] = (bf16_t)a[2]; r[3] = (bf16_t)a[3];
    *(bf16x4*)(wb + base) = r;
}

// K2: qkv = x @ qkv_w.T + b. bf16 weights from slab. 864 blocks.
// q/k/v bf16 planes [tok][head*32+d].
__global__ __launch_bounds__(256) void k_qkv(const float* __restrict__ x,
                                             const bf16_t* __restrict__ wb,
                                             const float* __restrict__ bias,
                                             bf16_t* __restrict__ qb,
                                             bf16_t* __restrict__ kb,
                                             bf16_t* __restrict__ vb) {
    const int wid = blockIdx.x * 4 + (threadIdx.x >> 6);   // 3456 waves
    const int m0 = (wid / 6) * 16;
    const int n0 = (wid % 6) * 64;
    const int lane = threadIdx.x & 63;
    const int g = lane >> 4, li = lane & 15;
    const float* ap = x + (m0 + li) * CC + g * 8;
    const bf16_t* bp = wb + W_QKV + (n0 + li) * CC + g * 8;
    f32x4 acc[4] = {};
    for (int k0 = 0; k0 < CC; k0 += 32) {
        bf16x8 a = cvt8(ap + k0);
#pragma unroll
        for (int t = 0; t < 4; t++) {
            bf16x8 b = *(const bf16x8*)(bp + t * 16 * CC + k0);
            acc[t] = __builtin_amdgcn_mfma_f32_16x16x32_bf16(a, b, acc[t], 0, 0, 0);
        }
    }
#pragma unroll
    for (int t = 0; t < 4; t++) {
        const int n = n0 + t * 16 + li;
        const float bb = bias[n];
        const int part = n >> 7, c = n & 127;
        bf16_t* dst = (part == 0) ? qb : (part == 1) ? kb : vb;
#pragma unroll
        for (int r = 0; r < 4; r++)
            dst[(m0 + g * 4 + r) * CC + c] = (bf16_t)(acc[t][r] + bb);
    }
}

// K3: na2d + proj per 4x4-token tile, 576 blocks, one wave per head.
// NO K/Q/V LDS staging: QK^T fragments load straight from the bf16 planes;
// V^T fragments are per-wave coalesced 2B gathers. LDS = Pbuf + o tile only.
__global__ __launch_bounds__(256, 4) void k_attn(
        const bf16_t* __restrict__ qb, const bf16_t* __restrict__ kg,
        const bf16_t* __restrict__ vg, const bf16_t* __restrict__ wb,
        const float* __restrict__ proj_b, bf16_t* __restrict__ x0g) {
    __shared__ __align__(16) bf16_t Pbuf[4 * 16 * STR];   // 17408 B
    __shared__ __align__(16) bf16_t o_s[16 * STR];        //  4352 B

    const int tid = threadIdx.x;
    const int w = tid >> 6, lane = tid & 63;
    const int g = lane >> 4, li = lane & 15;
    const int bid = blockIdx.x;
    const int i0 = (bid / 24) * 4, j0 = (bid % 24) * 4;
    const int pr0 = min(max(i0 - 3, 0), HH - PATCH);
    const int pc0 = min(max(j0 - 3, 0), WW - PATCH);
    const int head = w;
    const int ch = head * HD;    // this wave's 32-channel slice base

    // ---- phase 1: logits[16][112] = Q @ K^T, direct-global fragments ----
    f32x4 lg[7];
    {
        // q A-frag: token li of the 4x4 tile, channels ch+g*8..+7
        const int qi = i0 + (li >> 2), qj = j0 + (li & 3);
        const bf16x8 aq = *(const bf16x8*)(qb + (qi * WW + qj) * CC + ch + g * 8);
#pragma unroll
        for (int t = 0; t < 7; t++) {
            const int p = min(t * 16 + li, PSZ - 1);       // pad rows -> row 99
            const int pi = p / 10, pj = p - 10 * pi;
            const bf16x8 bk = *(const bf16x8*)(kg + ((pr0 + pi) * WW + pc0 + pj) * CC + ch + g * 8);
            lg[t] = __builtin_amdgcn_mfma_f32_16x16x32_bf16(aq, bk, (f32x4){0.f,0.f,0.f,0.f}, 0, 0, 0);
        }
    }
    // ---- mask + register softmax (row m=g*4+r, col nb=t*16+li) ----
    int lr[4], lc[4];
#pragma unroll
    for (int r = 0; r < 4; r++) {
        const int m = g * 4 + r;
        const int i = i0 + (m >> 2), j = j0 + (m & 3);
        lr[r] = min(max(i - 3, 0), HH - KW) - pr0;
        lc[r] = min(max(j - 3, 0), WW - KW) - pc0;
    }
    const float scale = 0.17677669529663687f;   // 1/sqrt(32)
#pragma unroll
    for (int t = 0; t < 7; t++) {
        const int col = t * 16 + li;
        const int pi = col / 10, pj = col - 10 * pi;
#pragma unroll
        for (int r = 0; r < 4; r++) {
            const bool valid = (col < PSZ) &&
                               ((unsigned)(pi - lr[r]) <= 6u) &&
                               ((unsigned)(pj - lc[r]) <= 6u);
            lg[t][r] = valid ? lg[t][r] * scale : -1e30f;
        }
    }
    f32x4 mx = lg[0], sm;
#pragma unroll
    for (int t = 1; t < 7; t++)
#pragma unroll
        for (int r = 0; r < 4; r++) mx[r] = fmaxf(mx[r], lg[t][r]);
#pragma unroll
    for (int off = 8; off; off >>= 1)
#pragma unroll
        for (int r = 0; r < 4; r++) mx[r] = fmaxf(mx[r], __shfl_xor(mx[r], off));
#pragma unroll
    for (int r = 0; r < 4; r++) sm[r] = 0.f;
#pragma unroll
    for (int t = 0; t < 7; t++)
#pragma unroll
        for (int r = 0; r < 4; r++) {
            lg[t][r] = __expf(lg[t][r] - mx[r]);
            sm[r] += lg[t][r];
        }
#pragma unroll
    for (int off = 8; off; off >>= 1)
#pragma unroll
        for (int r = 0; r < 4; r++) sm[r] += __shfl_xor(sm[r], off);
#pragma unroll
    for (int r = 0; r < 4; r++) sm[r] = 1.f / sm[r];

    // ---- P bf16 -> per-wave Pbuf (cols 112..127 zeroed) ----
    bf16_t* Pw = Pbuf + w * 16 * STR;
#pragma unroll
    for (int t = 0; t < 7; t++)
#pragma unroll
        for (int r = 0; r < 4; r++)
            Pw[(g * 4 + r) * STR + t * 16 + li] = (bf16_t)(lg[t][r] * sm[r]);
    *(bf16x4*)(Pw + (lane >> 2) * STR + NPAD + (lane & 3) * 4) = (bf16x4){0,0,0,0};
    __syncthreads();   // P visible (also covers same-wave write->read)

    // ---- phase 2: O[16][32] = P @ V^T; B-frags gathered from global ----
    f32x4 oA[2] = {};
#pragma unroll
    for (int ks0 = 0; ks0 < 128; ks0 += 32) {
        const bf16x8 a = *(const bf16x8*)(Pw + li * STR + ks0 + g * 8);
#pragma unroll
        for (int t2 = 0; t2 < 2; t2++) {
            bf16x8 b;
#pragma unroll
            for (int j = 0; j < 8; j++) {
                const int p = min(ks0 + g * 8 + j, PSZ - 1);   // P cols >=100 are 0
                const int pi = p / 10, pj = p - 10 * pi;
                b[j] = vg[((pr0 + pi) * WW + pc0 + pj) * CC + ch + t2 * 16 + li];
            }
            oA[t2] = __builtin_amdgcn_mfma_f32_16x16x32_bf16(a, b, oA[t2], 0, 0, 0);
        }
    }
    // ---- o -> LDS [16][STR] (cols ch..ch+31) ----
#pragma unroll
    for (int t2 = 0; t2 < 2; t2++)
#pragma unroll
        for (int r = 0; r < 4; r++)
            o_s[(g * 4 + r) * STR + ch + t2 * 16 + li] = (bf16_t)oA[t2][r];
    __syncthreads();

    // ---- proj: x0[16][128] = o @ proj_w^T + b; wave w -> cols w*32.. ----
    {
        f32x4 acc[2] = {};
        mmaN<2>(o_s, STR, wb + W_PROJ + (w * 32) * CC, CC, CC, acc);
#pragma unroll
        for (int t = 0; t < 2; t++) {
            const int n = w * 32 + t * 16 + li;
            const float bb = proj_b[n];
#pragma unroll
            for (int r = 0; r < 4; r++) {
                const int m = g * 4 + r;
                const int i = i0 + (m >> 2), j = j0 + (m & 3);
                x0g[(i * WW + j) * CC + n] = (bf16_t)(acc[t][r] + bb);
            }
        }
    }
}

// K4: MLP per 16 contiguous token rows. 576 blocks. A-frags direct from
// global x0; h1 [16][512] bf16 in LDS; fp32 out.
__global__ __launch_bounds__(256, 4) void k_mlp(const bf16_t* __restrict__ x0g,
                                                const bf16_t* __restrict__ wb,
                                                const float* __restrict__ fc1_b,
                                                const float* __restrict__ fc2_b,
                                                float* __restrict__ out) {
    __shared__ __align__(16) bf16_t h1s[16 * H1S];   // 16640 B
    const int w = threadIdx.x >> 6, lane = threadIdx.x & 63;
    const int g = lane >> 4, li = lane & 15;
    const int m0 = blockIdx.x * 16;

    {   // fc1 + gelu: wave w -> h1 cols [w*128, w*128+128)
        f32x4 acc[8] = {};
        mmaN<8>(x0g + m0 * CC, CC, wb + W_FC1 + (w * 128) * CC, CC, CC, acc);
#pragma unroll
        for (int t = 0; t < 8; t++) {
            const int n = w * 128 + t * 16 + li;
            const float bb = fc1_b[n];
#pragma unroll
            for (int r = 0; r < 4; r++) {
                const int m = g * 4 + r;
                const float xv = acc[t][r] + bb;
                const float u = 0.7978845608028654f * (xv + 0.044715f * xv * xv * xv);
                const float e = __expf(2.f * u);
                const float gg = 0.5f * xv * (2.f - 2.f / (e + 1.f));
                h1s[m * H1S + n] = (bf16_t)gg;
            }
        }
    }
    __syncthreads();
    {   // fc2: wave w -> out cols [w*32, w*32+32), K=512 from LDS
        f32x4 acc[2] = {};
        mmaN<2>(h1s, H1S, wb + W_FC2 + (w * 32) * (4 * CC), 4 * CC, 4 * CC, acc);
#pragma unroll
        for (int t = 0; t < 2; t++) {
            const int n = w * 32 + t * 16 + li;
            const float bb = fc2_b[n];
#pragma unroll
            for (int r = 0; r < 4; r++) {
                const int m = g * 4 + r;
                float xv = acc[t][r] + bb;
                xv = fminf(fmaxf(xv, -1e4f), 1e4f);   // diagnostic clamp
                out[(m0 + m) * CC + n] = xv;
            }
        }
    }
}

extern "C" void kernel_launch(void* const* d_in, const int* in_sizes, int n_in,
                              void* d_out, int out_size, void* d_ws, size_t ws_size,
                              hipStream_t stream) {
    const float* x      = (const float*)d_in[0];
    const float* qkv_w  = (const float*)d_in[1];
    const float* qkv_b  = (const float*)d_in[2];
    const float* proj_w = (const float*)d_in[3];
    const float* proj_b = (const float*)d_in[4];
    const float* fc1_w  = (const float*)d_in[5];
    const float* fc1_b  = (const float*)d_in[6];
    const float* fc2_w  = (const float*)d_in[7];
    const float* fc2_b  = (const float*)d_in[8];

    bf16_t* ws = (bf16_t*)d_ws;       // ws is ~268 MB (from fill WRITE_SIZE)
    bf16_t* qb = ws;                  // [9216][128] bf16
    bf16_t* kb = ws + PLANE;
    bf16_t* vb = ws + 2 * PLANE;
    bf16_t* x0 = ws + 3 * PLANE;
    bf16_t* wb = ws + 4 * PLANE;      // 196608-elem bf16 weight slab
    float* out = (float*)d_out;

    k_cvt <<<192, 256, 0, stream>>>(qkv_w, proj_w, fc1_w, fc2_w, wb);
    k_qkv <<<864, 256, 0, stream>>>(x, wb, qkv_b, qb, kb, vb);
    k_attn<<<576, 256, 0, stream>>>(qb, kb, vb, wb, proj_b, x0);
    k_mlp <<<576, 256, 0, stream>>>(x0, wb, fc1_b, fc2_b, out);
}